// Round 1
// baseline (555.826 us; speedup 1.0000x reference)
//
#include <hip/hip_runtime.h>

// out[n,o,z,y,x] = b[o] + sum_{kd, d=z+kd-2 in [0,10)} sum_{kh,kw}
//                  x[n,d,y+kh-2,x+kw-2] * W[o,d,kd,kh,kw]
// Diagonal-embed Conv3d == per-z sum of <=5 2D 5x5 convs.
//
// This version: one block computes a z-PAIR (z0, z0+1) so each staged input
// plane d feeds up to 2 z's (planes/(n,tile): 44 -> 26). Staging is direct
// global->LDS DMA (global_load_lds, 4B), double-buffered and issued one
// plane ahead so HBM/L2 latency hides under the FMA stream. One barrier
// per plane. FP accumulation order identical to previous kernel.

#define TILE_ROWS 8
#define LDS_ROWS  12                      // TILE_ROWS + 4 halo
#define LDS_W     132                     // 128 + 4 halo (528B rows, 16B-aligned)
#define PLANE_W   (LDS_ROWS * LDS_W)      // 1584 words per plane buffer
#define BLOCK     256
#define NSLOT     7                       // ceil(1584/256)

typedef const __attribute__((address_space(1))) void gvoid_t;
typedef __attribute__((address_space(3))) void lvoid_t;

__global__ __launch_bounds__(BLOCK, 4)
void conv3d_diag_kernel(const float* __restrict__ x,     // [32,10,128,128]
                        const float* __restrict__ Wt,    // [10,10,5,5,5] OIDHW
                        const float* __restrict__ bias,  // [10]
                        float* __restrict__ out)         // [32,10,10,128,128]
{
    __shared__ float lds[2 * PLANE_W];    // double-buffered plane tiles (12.7 KB)

    const int tid  = threadIdx.x;
    const int tile = blockIdx.x;          // 0..15  (row tile)
    const int z0   = blockIdx.y << 1;     // 0,2,4,6,8 (z-pair base)
    const int n    = blockIdx.z;          // 0..31  (batch)

    const int y0 = tile * TILE_ROWS;
    const int tx = tid & 31;              // 0..31 -> 4-wide column group
    const int ty = tid >> 5;              // 0..7  -> row within tile
    const int x0 = tx << 2;               // output column base
    const int y  = y0 + ty;               // output row

    // ---- plane-independent staging geometry (computed ONCE) ----
    // slot s stages LDS word e = tid + 256*s from x-plane offset goff[s];
    // goff[s] < 0 marks "no load" (OOB halo / e >= PLANE_W) -> lane masked
    // off the DMA, cell keeps its pre-zeroed value.
    int goff[NSLOT];
    #pragma unroll
    for (int s = 0; s < NSLOT; ++s) {
        const int e  = tid + s * BLOCK;
        const int r  = e / LDS_W;         // one-time magic-mul div
        const int c  = e - r * LDS_W;
        const int gr = y0 - 2 + r;
        const int gc = c - 2;
        const bool ok = (e < PLANE_W) && ((unsigned)gr < 128u) && ((unsigned)gc < 128u);
        goff[s] = ok ? (gr * 128 + gc) : -1;
    }
    const int lbase = tid & ~63;          // wave-uniform LDS lane base (DMA dest)

    // Pre-zero both buffers: pad cells are never written by the DMA and must
    // read as 0 for every plane; valid cells get rewritten each plane.
    for (int e = tid; e < 2 * PLANE_W; e += BLOCK) lds[e] = 0.f;

    float acc[2][10][4];
    #pragma unroll
    for (int zi = 0; zi < 2; ++zi)
        #pragma unroll
        for (int o = 0; o < 10; ++o)
            #pragma unroll
            for (int p = 0; p < 4; ++p) acc[zi][o][p] = 0.f;

    const float* xn = x + (size_t)n * (10 * 128 * 128);
    const int d_lo = (z0 >= 2) ? z0 - 2 : 0;
    const int d_hi = (z0 + 3 <= 9) ? z0 + 3 : 9;

    __syncthreads();                      // zero-fill visible before first DMA

    // ---- prologue: DMA plane d_lo -> buffer 0 ----
    {
        const float* xp = xn + d_lo * (128 * 128);
        #pragma unroll
        for (int s = 0; s < NSLOT; ++s)
            if (goff[s] >= 0)
                __builtin_amdgcn_global_load_lds((gvoid_t*)(xp + goff[s]),
                                                 (lvoid_t*)(lds + s * BLOCK + lbase),
                                                 4, 0, 0);
    }
    __syncthreads();                      // vmcnt(0) drain + barrier: buf0 ready

    int cur = 0;
    #pragma unroll 1
    for (int d = d_lo; d <= d_hi; ++d) {
        // Issue next plane's DMA into the OTHER buffer before computing —
        // latency hides under ~2000 FMAs of this plane.
        if (d < d_hi) {
            const float* xp = xn + (d + 1) * (128 * 128);
            float* nb = lds + (cur ^ 1) * PLANE_W;
            #pragma unroll
            for (int s = 0; s < NSLOT; ++s)
                if (goff[s] >= 0)
                    __builtin_amdgcn_global_load_lds((gvoid_t*)(xp + goff[s]),
                                                     (lvoid_t*)(nb + s * BLOCK + lbase),
                                                     4, 0, 0);
        }

        const float* bc  = lds + cur * PLANE_W;
        const int  kd0 = d - z0 + 2;               // kd for z0 (block-uniform)
        const int  kd1 = kd0 - 1;                  // kd for z0+1
        const bool do0 = (unsigned)kd0 < 5u;       // uniform branches
        const bool do1 = (unsigned)kd1 < 5u;
        const float* wd = Wt + d * 125;

        #pragma unroll
        for (int kh = 0; kh < 5; ++kh) {
            // 8 input floats covering cols x0-2 .. x0+5 (halo offset +2);
            // (ty+kh)*LDS_W + x0 is float4-aligned; kh folds into ds offsets.
            const float* lp = bc + (ty + kh) * LDS_W + x0;
            const float4 rlo = *(const float4*)(lp);
            const float4 rhi = *(const float4*)(lp + 4);
            const float r[8] = {rlo.x, rlo.y, rlo.z, rlo.w,
                                rhi.x, rhi.y, rhi.z, rhi.w};

            if (do0) {
                // Weights W[o,d,kd0,kh,kw]: uniform address -> scalar loads.
                const float* wp = wd + kd0 * 25 + kh * 5;
                #pragma unroll
                for (int kw = 0; kw < 5; ++kw)
                    #pragma unroll
                    for (int o = 0; o < 10; ++o) {
                        const float wv = wp[o * 1250 + kw];
                        #pragma unroll
                        for (int p = 0; p < 4; ++p)
                            acc[0][o][p] += r[p + kw] * wv;
                    }
            }
            if (do1) {
                const float* wp = wd + kd1 * 25 + kh * 5;
                #pragma unroll
                for (int kw = 0; kw < 5; ++kw)
                    #pragma unroll
                    for (int o = 0; o < 10; ++o) {
                        const float wv = wp[o * 1250 + kw];
                        #pragma unroll
                        for (int p = 0; p < 4; ++p)
                            acc[1][o][p] += r[p + kw] * wv;
                    }
            }
        }

        if (d < d_hi) {
            __syncthreads();   // drains DMA (vmcnt) + all reads of bc done
            cur ^= 1;
        }
    }

    // ---- epilogue: bias + 20 coalesced float4 stores ----
    #pragma unroll
    for (int zi = 0; zi < 2; ++zi) {
        const int z = z0 + zi;
        #pragma unroll
        for (int o = 0; o < 10; ++o) {
            const float bo = bias[o];
            const float4 v = make_float4(acc[zi][o][0] + bo, acc[zi][o][1] + bo,
                                         acc[zi][o][2] + bo, acc[zi][o][3] + bo);
            const size_t idx = ((((size_t)n * 10 + o) * 10 + z) * 128 + y) * 128 + x0;
            *(float4*)(out + idx) = v;
        }
    }
}

extern "C" void kernel_launch(void* const* d_in, const int* in_sizes, int n_in,
                              void* d_out, int out_size, void* d_ws, size_t ws_size,
                              hipStream_t stream) {
    const float* x    = (const float*)d_in[0];  // [32,10,128,128]
    const float* Wt   = (const float*)d_in[1];  // [10,10,5,5,5]
    const float* bias = (const float*)d_in[2];  // [10]
    float* out = (float*)d_out;                 // [32,10,10,128,128]

    dim3 grid(16, 5, 32);   // (row tiles, z-pairs, n) = 2560 blocks
    conv3d_diag_kernel<<<grid, BLOCK, 0, stream>>>(x, Wt, bias, out);
}

// Round 2
// 445.609 us; speedup vs baseline: 1.2473x; 1.2473x over previous
//
#include <hip/hip_runtime.h>

// out[n,o,z,y,x] = b[o] + sum_{kd, d=z+kd-2 in [0,10)} sum_{kh,kw}
//                  x[n,d,y+kh-2,x+kw-2] * W[o,d,kd,kh,kw]
// Diagonal-embed Conv3d == per-z sum of <=5 2D 5x5 convs.
//
// Round-2: single-z accumulators (acc[10][4] = 40 VGPR -- round-1's z-pair
// acc[2][10][4] spilled to scratch: WRITE_SIZE 205MB->947MB). Keeps the
// good parts of round-1: one-time staging geometry, direct global->LDS DMA
// (global_load_lds, no ds_write / no staging VALU), double-buffered planes
// with the next plane's DMA issued BEFORE computing the current one, and a
// single barrier per plane. FP accumulation order identical to round-0.

#define TILE_ROWS 8
#define LDS_ROWS  12                      // TILE_ROWS + 4 halo
#define LDS_W     132                     // 128 + 4 halo (528B rows, 16B-aligned)
#define PLANE_W   (LDS_ROWS * LDS_W)      // 1584 words per plane buffer
#define BLOCK     256
#define NSLOT     7                       // ceil(1584/256)

typedef const __attribute__((address_space(1))) void gvoid_t;
typedef __attribute__((address_space(3))) void lvoid_t;

__global__ __launch_bounds__(BLOCK, 4)
void conv3d_diag_kernel(const float* __restrict__ x,     // [32,10,128,128]
                        const float* __restrict__ Wt,    // [10,10,5,5,5] OIDHW
                        const float* __restrict__ bias,  // [10]
                        float* __restrict__ out)         // [32,10,10,128,128]
{
    __shared__ float lds[2 * PLANE_W];    // double-buffered plane tiles (12.7 KB)

    const int tid  = threadIdx.x;
    const int tile = blockIdx.x;          // 0..15  (row tile)
    const int z    = blockIdx.y;          // 0..9   (output depth)
    const int n    = blockIdx.z;          // 0..31  (batch)

    const int y0 = tile * TILE_ROWS;
    const int tx = tid & 31;              // 0..31 -> 4-wide column group
    const int ty = tid >> 5;              // 0..7  -> row within tile
    const int x0 = tx << 2;               // output column base
    const int y  = y0 + ty;               // output row

    // ---- plane-independent staging geometry (computed ONCE) ----
    // slot s stages LDS word e = tid + 256*s from x-plane offset goff[s];
    // goff[s] < 0 marks "no load" (OOB halo / e >= PLANE_W) -> lane masked
    // off the DMA, cell keeps its pre-zeroed value.
    int goff[NSLOT];
    #pragma unroll
    for (int s = 0; s < NSLOT; ++s) {
        const int e  = tid + s * BLOCK;
        const int r  = e / LDS_W;         // one-time magic-mul div
        const int c  = e - r * LDS_W;
        const int gr = y0 - 2 + r;
        const int gc = c - 2;
        const bool ok = (e < PLANE_W) && ((unsigned)gr < 128u) && ((unsigned)gc < 128u);
        goff[s] = ok ? (gr * 128 + gc) : -1;
    }
    const int lbase = tid & ~63;          // wave-uniform LDS lane base (DMA dest)

    // Pre-zero both buffers: pad cells are never written by the DMA and must
    // read as 0 for every plane; valid cells get rewritten each plane.
    for (int e = tid; e < 2 * PLANE_W; e += BLOCK) lds[e] = 0.f;

    float acc[10][4];
    #pragma unroll
    for (int o = 0; o < 10; ++o)
        #pragma unroll
        for (int p = 0; p < 4; ++p) acc[o][p] = 0.f;

    const float* xn = x + (size_t)n * (10 * 128 * 128);
    const int d_lo = (z >= 2) ? z - 2 : 0;
    const int d_hi = (z + 2 <= 9) ? z + 2 : 9;

    __syncthreads();                      // zero-fill visible before first DMA

    // ---- prologue: DMA plane d_lo -> buffer 0 ----
    {
        const float* xp = xn + d_lo * (128 * 128);
        #pragma unroll
        for (int s = 0; s < NSLOT; ++s)
            if (goff[s] >= 0)
                __builtin_amdgcn_global_load_lds((gvoid_t*)(xp + goff[s]),
                                                 (lvoid_t*)(lds + s * BLOCK + lbase),
                                                 4, 0, 0);
    }
    __syncthreads();                      // vmcnt drain + barrier: buf0 ready

    int cur = 0;
    #pragma unroll 1
    for (int d = d_lo; d <= d_hi; ++d) {
        // Issue next plane's DMA into the OTHER buffer before computing —
        // its latency hides under this plane's ~1000 FMAs.
        if (d < d_hi) {
            const float* xp = xn + (d + 1) * (128 * 128);
            float* nb = lds + (cur ^ 1) * PLANE_W;
            #pragma unroll
            for (int s = 0; s < NSLOT; ++s)
                if (goff[s] >= 0)
                    __builtin_amdgcn_global_load_lds((gvoid_t*)(xp + goff[s]),
                                                     (lvoid_t*)(nb + s * BLOCK + lbase),
                                                     4, 0, 0);
        }

        const float* bc = lds + cur * PLANE_W;
        const int    kd = d - z + 2;      // in [0,4] by d-range construction
        const float* wk = Wt + (size_t)(d * 125 + kd * 25);

        #pragma unroll
        for (int kh = 0; kh < 5; ++kh) {
            // Weights W[o,d,kd,kh,kw]; uniform address -> scalar loads.
            const float* wp = wk + kh * 5;
            float wv[10][5];
            #pragma unroll
            for (int o = 0; o < 10; ++o)
                #pragma unroll
                for (int kw = 0; kw < 5; ++kw)
                    wv[o][kw] = wp[o * 1250 + kw];

            // 8 input floats covering cols x0-2 .. x0+5 (halo offset +2):
            // (ty+kh)*LDS_W + x0 is float4-aligned.
            const float* lp = bc + (ty + kh) * LDS_W + x0;
            const float4 rlo = *(const float4*)(lp);
            const float4 rhi = *(const float4*)(lp + 4);
            const float r[8] = {rlo.x, rlo.y, rlo.z, rlo.w,
                                rhi.x, rhi.y, rhi.z, rhi.w};

            #pragma unroll
            for (int kw = 0; kw < 5; ++kw)
                #pragma unroll
                for (int o = 0; o < 10; ++o)
                    #pragma unroll
                    for (int p = 0; p < 4; ++p)
                        acc[o][p] += r[p + kw] * wv[o][kw];
        }

        if (d < d_hi) {
            __syncthreads();   // drains next-plane DMA; all reads of bc done
            cur ^= 1;
        }
    }

    // ---- epilogue: bias + 10 coalesced float4 stores ----
    #pragma unroll
    for (int o = 0; o < 10; ++o) {
        const float bo = bias[o];
        const float4 v = make_float4(acc[o][0] + bo, acc[o][1] + bo,
                                     acc[o][2] + bo, acc[o][3] + bo);
        const size_t idx = ((((size_t)n * 10 + o) * 10 + z) * 128 + y) * 128 + x0;
        *(float4*)(out + idx) = v;
    }
}

extern "C" void kernel_launch(void* const* d_in, const int* in_sizes, int n_in,
                              void* d_out, int out_size, void* d_ws, size_t ws_size,
                              hipStream_t stream) {
    const float* x    = (const float*)d_in[0];  // [32,10,128,128]
    const float* Wt   = (const float*)d_in[1];  // [10,10,5,5,5]
    const float* bias = (const float*)d_in[2];  // [10]
    float* out = (float*)d_out;                 // [32,10,10,128,128]

    dim3 grid(16, 10, 32);   // (row tiles, z, n) = 5120 blocks
    conv3d_diag_kernel<<<grid, BLOCK, 0, stream>>>(x, Wt, bias, out);
}

// Round 3
// 297.387 us; speedup vs baseline: 1.8690x; 1.4984x over previous
//
#include <hip/hip_runtime.h>

// out[n,o,z,y,x] = b[o] + sum_{kd, d=z+kd-2 in [0,10)} sum_{kh,kw}
//                  x[n,d,y+kh-2,x+kw-2] * W[o,d,kd,kh,kw]
// Diagonal-embed Conv3d == per-z sum of <=5 2D 5x5 convs.
//
// Round-3: round-0's PROVEN compute structure (kh loop with #pragma unroll 1
// so only 50 uniform weight loads are live at once -> they stay in SGPRs;
// round-2's full kh unroll needed 250 weights, blew the SGPR budget, and
// demoted weights to the VALU path: VALU-busy time 109us -> 255us) combined
// with round-2's cheap staging (one-time geometry, global->LDS DMA, double
// buffer, next plane issued before compute, ONE barrier per plane).
// FP accumulation order identical to round-0.

#define TILE_ROWS 8
#define LDS_ROWS  12                      // TILE_ROWS + 4 halo
#define LDS_W     132                     // 128 + 4 halo (528B rows, 16B-aligned)
#define PLANE_W   (LDS_ROWS * LDS_W)      // 1584 words per plane buffer
#define BLOCK     256
#define NSLOT     7                       // ceil(1584/256)

typedef const __attribute__((address_space(1))) void gvoid_t;
typedef __attribute__((address_space(3))) void lvoid_t;

__global__ __launch_bounds__(BLOCK, 4)
void conv3d_diag_kernel(const float* __restrict__ x,     // [32,10,128,128]
                        const float* __restrict__ Wt,    // [10,10,5,5,5] OIDHW
                        const float* __restrict__ bias,  // [10]
                        float* __restrict__ out)         // [32,10,10,128,128]
{
    __shared__ float lds[2 * PLANE_W];    // double-buffered plane tiles (12.7 KB)

    const int tid  = threadIdx.x;
    const int tile = blockIdx.x;          // 0..15  (row tile)
    const int z    = blockIdx.y;          // 0..9   (output depth)
    const int n    = blockIdx.z;          // 0..31  (batch)

    const int y0 = tile * TILE_ROWS;
    const int tx = tid & 31;              // 0..31 -> 4-wide column group
    const int ty = tid >> 5;              // 0..7  -> row within tile
    const int x0 = tx << 2;               // output column base
    const int y  = y0 + ty;               // output row

    // ---- plane-independent staging geometry (computed ONCE) ----
    // slot s stages LDS word e = tid + 256*s from x-plane offset goff[s];
    // goff[s] < 0 marks "no load" (OOB halo / e >= PLANE_W) -> lane masked
    // off the DMA, cell keeps its pre-zeroed value.
    int goff[NSLOT];
    #pragma unroll
    for (int s = 0; s < NSLOT; ++s) {
        const int e  = tid + s * BLOCK;
        const int r  = e / LDS_W;         // one-time magic-mul div
        const int c  = e - r * LDS_W;
        const int gr = y0 - 2 + r;
        const int gc = c - 2;
        const bool ok = (e < PLANE_W) && ((unsigned)gr < 128u) && ((unsigned)gc < 128u);
        goff[s] = ok ? (gr * 128 + gc) : -1;
    }
    const int lbase = tid & ~63;          // wave-uniform LDS lane base (DMA dest)

    // Pre-zero both buffers: pad cells are never written by the DMA and must
    // read as 0 for every plane; valid cells get rewritten each plane.
    for (int e = tid; e < 2 * PLANE_W; e += BLOCK) lds[e] = 0.f;

    float acc[10][4];
    #pragma unroll
    for (int o = 0; o < 10; ++o)
        #pragma unroll
        for (int p = 0; p < 4; ++p) acc[o][p] = 0.f;

    const float* xn = x + (size_t)n * (10 * 128 * 128);
    const int d_lo = (z >= 2) ? z - 2 : 0;
    const int d_hi = (z + 2 <= 9) ? z + 2 : 9;

    __syncthreads();                      // zero-fill visible before first DMA

    // ---- prologue: DMA plane d_lo -> buffer 0 ----
    {
        const float* xp = xn + d_lo * (128 * 128);
        #pragma unroll
        for (int s = 0; s < NSLOT; ++s)
            if (goff[s] >= 0)
                __builtin_amdgcn_global_load_lds((gvoid_t*)(xp + goff[s]),
                                                 (lvoid_t*)(lds + s * BLOCK + lbase),
                                                 4, 0, 0);
    }
    __syncthreads();                      // vmcnt drain + barrier: buf0 ready

    int cur = 0;
    #pragma unroll 1
    for (int d = d_lo; d <= d_hi; ++d) {
        // Issue next plane's DMA into the OTHER buffer before computing —
        // its latency hides under this plane's ~1000 FMAs.
        if (d < d_hi) {
            const float* xp = xn + (d + 1) * (128 * 128);
            float* nb = lds + (cur ^ 1) * PLANE_W;
            #pragma unroll
            for (int s = 0; s < NSLOT; ++s)
                if (goff[s] >= 0)
                    __builtin_amdgcn_global_load_lds((gvoid_t*)(xp + goff[s]),
                                                     (lvoid_t*)(nb + s * BLOCK + lbase),
                                                     4, 0, 0);
        }

        const float* bc = lds + cur * PLANE_W;
        const int    kd = d - z + 2;      // in [0,4] by d-range construction

        #pragma unroll 1
        for (int kh = 0; kh < 5; ++kh) {
            // Weights W[o,d,kd,kh,kw]; uniform address -> scalar (SGPR) loads.
            // unroll 1 keeps only 50 weights live -> fits the SGPR file.
            const float* wp = Wt + (size_t)(d * 125 + kd * 25 + kh * 5);
            float wv[10][5];
            #pragma unroll
            for (int o = 0; o < 10; ++o)
                #pragma unroll
                for (int kw = 0; kw < 5; ++kw)
                    wv[o][kw] = wp[o * 1250 + kw];

            // 8 input floats covering cols x0-2 .. x0+5 (halo offset +2):
            // (ty+kh)*LDS_W + x0 is float4-aligned.
            const float* lp = bc + (ty + kh) * LDS_W + x0;
            const float4 rlo = *(const float4*)(lp);
            const float4 rhi = *(const float4*)(lp + 4);
            const float r[8] = {rlo.x, rlo.y, rlo.z, rlo.w,
                                rhi.x, rhi.y, rhi.z, rhi.w};

            #pragma unroll
            for (int kw = 0; kw < 5; ++kw)
                #pragma unroll
                for (int o = 0; o < 10; ++o)
                    #pragma unroll
                    for (int p = 0; p < 4; ++p)
                        acc[o][p] += r[p + kw] * wv[o][kw];
        }

        if (d < d_hi) {
            __syncthreads();   // drains next-plane DMA; all reads of bc done
            cur ^= 1;
        }
    }

    // ---- epilogue: bias + 10 coalesced float4 stores ----
    #pragma unroll
    for (int o = 0; o < 10; ++o) {
        const float bo = bias[o];
        const float4 v = make_float4(acc[o][0] + bo, acc[o][1] + bo,
                                     acc[o][2] + bo, acc[o][3] + bo);
        const size_t idx = ((((size_t)n * 10 + o) * 10 + z) * 128 + y) * 128 + x0;
        *(float4*)(out + idx) = v;
    }
}

extern "C" void kernel_launch(void* const* d_in, const int* in_sizes, int n_in,
                              void* d_out, int out_size, void* d_ws, size_t ws_size,
                              hipStream_t stream) {
    const float* x    = (const float*)d_in[0];  // [32,10,128,128]
    const float* Wt   = (const float*)d_in[1];  // [10,10,5,5,5]
    const float* bias = (const float*)d_in[2];  // [10]
    float* out = (float*)d_out;                 // [32,10,10,128,128]

    dim3 grid(16, 10, 32);   // (row tiles, z, n) = 5120 blocks
    conv3d_diag_kernel<<<grid, BLOCK, 0, stream>>>(x, Wt, bias, out);
}